// Round 7
// baseline (497.075 us; speedup 1.0000x reference)
//
#include <hip/hip_runtime.h>

#define NN0 600000
#define NN1 100000
#define NN2 20000
#define NN3 4096
#define EE0 1500000
#define EE1 200000
#define EE2 40960
#define DIN 100
#define DH  256
#define DOUT 47
#define NTOT (NN1 + NN2 + NN3)   // 124096
#define NG 64                     // counter partitions

// fused scan geometry: ceil(N/1024) blocks per layer
#define NB0 98
#define NB1 20
#define NB2 4
#define NBT 122

// one-edge-per-thread block counts (256 thr/block)
#define HB0 5860
#define HB1 782
#define HB2 160
#define HBE (HB0 + HB1 + HB2)
#define PACKBLK 108
#define CONVBLK 3072

typedef unsigned int uint;
typedef unsigned short ushort;
typedef __attribute__((ext_vector_type(8))) short bhalf8;
typedef __attribute__((ext_vector_type(4))) float f32x4;

union U16B {
    uint2  u2[2];
    uint4  u4;
    bhalf8 s8;
    ushort us[8];
};

__device__ __forceinline__ ushort f2bf(float f) {
    uint u = __float_as_uint(f);
    uint r = (u + 0x7FFFu + ((u >> 16) & 1u)) >> 16;
    return (ushort)r;
}
__device__ __forceinline__ float bf2f(uint bits16) {
    return __uint_as_float(bits16 << 16);
}

// ================= weight pack helper =======================================
__device__ __forceinline__ void pack_one(const float* B, int K, int N, int NB,
                                         ushort* out, int bid, int l) {
    int kstep = bid / NB;
    int c = bid % NB;
    U16B v;
    #pragma unroll
    for (int j = 0; j < 8; ++j) {
        int k = kstep * 32 + ((l >> 4) << 3) + j;
        int col = (c << 4) | (l & 15);
        float f = (k < K && col < N) ? B[(size_t)k * N + col] : 0.0f;
        v.us[j] = f2bf(f);
    }
    *reinterpret_cast<bhalf8*>(out + ((size_t)bid * 64 + l) * 8) = v.s8;
}

// ================= K1: partitioned hist (return = rank) + conv + pack ========
// cntp layout: [NG][NTOT]. group g = (layer-local block) & 63.
__global__ __launch_bounds__(256)
void hist_conv(const int* __restrict__ e0d, const int* __restrict__ e1d,
               const int* __restrict__ e2d, int* __restrict__ cntp,
               int* __restrict__ pos0, int* __restrict__ pos1, int* __restrict__ pos2,
               const float* __restrict__ x, ushort* __restrict__ xb, long long n4,
               const float* __restrict__ Wl0, const float* __restrict__ Wr0,
               const float* __restrict__ Wl1, const float* __restrict__ Wr1,
               const float* __restrict__ Wl2, const float* __restrict__ Wr2,
               ushort* Bp0l, ushort* Bp0r, ushort* Bp1l, ushort* Bp1r,
               ushort* Bp2l, ushort* Bp2r) {
    int b = blockIdx.x;
    int tid = threadIdx.x;
    if (b < HB0) {
        int e = b * 256 + tid;
        if (e < EE0) {
            int g = b & (NG - 1);
            int p = atomicAdd(&cntp[(size_t)g * NTOT + e0d[e]], 1);
            pos0[e] = p;
        }
    } else if (b < HB0 + HB1) {
        int bb = b - HB0;
        int e = bb * 256 + tid;
        if (e < EE1) {
            int g = bb & (NG - 1);
            int p = atomicAdd(&cntp[(size_t)g * NTOT + NN1 + e1d[e]], 1);
            pos1[e] = p;
        }
    } else if (b < HBE) {
        int bb = b - HB0 - HB1;
        int e = bb * 256 + tid;
        if (e < EE2) {
            int g = bb & (NG - 1);
            int p = atomicAdd(&cntp[(size_t)g * NTOT + NN1 + NN2 + e2d[e]], 1);
            pos2[e] = p;
        }
    } else if (b < HBE + CONVBLK) {
        int cb = b - HBE;
        for (long long t = (long long)cb * 256 + tid; t < n4;
             t += (long long)CONVBLK * 256) {
            float4 v = *reinterpret_cast<const float4*>(x + t * 4);
            uint2 o;
            o.x = (uint)f2bf(v.x) | ((uint)f2bf(v.y) << 16);
            o.y = (uint)f2bf(v.z) | ((uint)f2bf(v.w) << 16);
            *reinterpret_cast<uint2*>(xb + t * 4) = o;
        }
    } else {
        int bid = (b - HBE - CONVBLK) * 4 + (tid >> 6);
        int l = tid & 63;
        if (bid < 64)       pack_one(Wl0, DIN, DH,  16, Bp0l, bid,       l);
        else if (bid < 128) pack_one(Wr0, DIN, DH,  16, Bp0r, bid - 64,  l);
        else if (bid < 256) pack_one(Wl1, DH,  DH,  16, Bp1l, bid - 128, l);
        else if (bid < 384) pack_one(Wr1, DH,  DH,  16, Bp1r, bid - 256, l);
        else if (bid < 408) pack_one(Wl2, DH,  DOUT, 3, Bp2l, bid - 384, l);
        else                pack_one(Wr2, DH,  DOUT, 3, Bp2r, bid - 408, l);
    }
}

// ================= K2: in-place exclusive scan over partitions ==============
// After this, cntp[g][i] = number of edges for node i in groups < g, and
// cntAll[i] = total count.
__global__ __launch_bounds__(256)
void combine_parts(int* __restrict__ cntp, int* __restrict__ cntAll) {
    int i = blockIdx.x * 256 + threadIdx.x;
    if (i >= NTOT) return;
    int run = 0;
    #pragma unroll 8
    for (int g = 0; g < NG; ++g) {
        size_t idx = (size_t)g * NTOT + i;
        int v = cntp[idx];
        cntp[idx] = run;
        run += v;
    }
    cntAll[i] = run;
}

// ================= fused CSR scans ==========================================

__device__ __forceinline__ void layer_of(int b, int& lb, int& n, int& po, int& cb) {
    if (b < NB0)      { lb = b;        n = NN1; po = 0;         cb = 0; }
    else if (b < NB0 + NB1) { lb = b - NB0;  n = NN2; po = NB0; cb = NN1; }
    else              { lb = b - NB0 - NB1; n = NN3; po = NB0 + NB1; cb = NN1 + NN2; }
}

__global__ void scan1f(const int* __restrict__ cntAll, int* __restrict__ part) {
    int lb, n, po, cb;
    layer_of(blockIdx.x, lb, n, po, cb);
    __shared__ int s[256];
    int base = lb * 1024;
    int sum = 0;
    for (int i = threadIdx.x; i < 1024; i += 256) {
        int idx = base + i;
        sum += (idx < n) ? cntAll[cb + idx] : 0;
    }
    s[threadIdx.x] = sum;
    __syncthreads();
    for (int off = 128; off; off >>= 1) {
        if (threadIdx.x < off) s[threadIdx.x] += s[threadIdx.x + off];
        __syncthreads();
    }
    if (threadIdx.x == 0) part[po + lb] = s[0];
}

__global__ void scan2f(int* part) {
    __shared__ int s[128];
    int t = threadIdx.x;
    int seg = (t < NB0) ? 0 : (t < NB0 + NB1) ? 1 : (t < NBT) ? 2 : 3;
    int v = (t < NBT) ? part[t] : 0;
    s[t] = v;
    __syncthreads();
    for (int off = 1; off < 128; off <<= 1) {
        int add = 0;
        if (t >= off) {
            int u = t - off;
            int segu = (u < NB0) ? 0 : (u < NB0 + NB1) ? 1 : (u < NBT) ? 2 : 3;
            if (segu == seg) add = s[u];
        }
        __syncthreads();
        s[t] += add;
        __syncthreads();
    }
    if (t < NBT) part[t] = s[t] - v;
}

__global__ void scan3f(const int* __restrict__ cntAll, const int* __restrict__ part,
                       int* __restrict__ rp0, int* __restrict__ rp1,
                       int* __restrict__ rp2) {
    int lb, n, po, cb;
    layer_of(blockIdx.x, lb, n, po, cb);
    int* row_ptr;
    if (cb == 0)        row_ptr = rp0;
    else if (cb == NN1) row_ptr = rp1;
    else                row_ptr = rp2;

    __shared__ int s[256];
    int base = lb * 1024;
    int v[4];
    int sum = 0;
    #pragma unroll
    for (int j = 0; j < 4; ++j) {
        int idx = base + threadIdx.x * 4 + j;
        v[j] = (idx < n) ? cntAll[cb + idx] : 0;
        sum += v[j];
    }
    s[threadIdx.x] = sum;
    __syncthreads();
    for (int off = 1; off < 256; off <<= 1) {
        int t = (threadIdx.x >= off) ? s[threadIdx.x - off] : 0;
        __syncthreads();
        s[threadIdx.x] += t;
        __syncthreads();
    }
    int off0 = part[po + lb] + s[threadIdx.x] - sum;
    #pragma unroll
    for (int j = 0; j < 4; ++j) {
        int idx = base + threadIdx.x * 4 + j;
        if (idx < n) {
            row_ptr[idx] = off0;
            off0 += v[j];
            if (idx == n - 1) row_ptr[n] = off0;
        }
    }
}

// ================= K3: atomic-free placement ================================
__global__ __launch_bounds__(256)
void place_all(const int* __restrict__ e0s, const int* __restrict__ e0d,
               const int* __restrict__ e1s, const int* __restrict__ e1d,
               const int* __restrict__ e2s, const int* __restrict__ e2d,
               const int* __restrict__ pos0, const int* __restrict__ pos1,
               const int* __restrict__ pos2, const int* __restrict__ cntp,
               const int* __restrict__ rp0, const int* __restrict__ rp1,
               const int* __restrict__ rp2,
               int* __restrict__ eidx0, int* __restrict__ eidx1,
               int* __restrict__ eidx2) {
    int b = blockIdx.x;
    int tid = threadIdx.x;
    if (b < HB0) {
        int e = b * 256 + tid;
        if (e < EE0) {
            int d = e0d[e];
            int g = b & (NG - 1);
            int p = rp0[d] + cntp[(size_t)g * NTOT + d] + pos0[e];
            eidx0[p] = e0s[e];
        }
    } else if (b < HB0 + HB1) {
        int bb = b - HB0;
        int e = bb * 256 + tid;
        if (e < EE1) {
            int d = e1d[e];
            int g = bb & (NG - 1);
            int p = rp1[d] + cntp[(size_t)g * NTOT + NN1 + d] + pos1[e];
            eidx1[p] = e1s[e];
        }
    } else {
        int bb = b - HB0 - HB1;
        int e = bb * 256 + tid;
        if (e < EE2) {
            int d = e2d[e];
            int g = bb & (NG - 1);
            int p = rp2[d] + cntp[(size_t)g * NTOT + NN1 + NN2 + d] + pos2[e];
            eidx2[p] = e2s[e];
        }
    }
}

// ================= pull aggregation (fp32 accum, bf16 out, mean folded) ======

__global__ __launch_bounds__(256)
void agg100_b(const ushort* __restrict__ xb, const int* __restrict__ rp,
              const int* __restrict__ eidx, ushort* __restrict__ out, int nNodes) {
    int node = blockIdx.x * 4 + (threadIdx.x >> 6);
    if (node >= nNodes) return;
    int l = threadIdx.x & 63;
    bool act = l < 50;
    int beg = rp[node], end = rp[node + 1];
    float a0 = 0.f, a1 = 0.f;
    int j = beg;
    for (; j + 3 < end; j += 4) {
        int s0 = eidx[j], s1 = eidx[j + 1], s2 = eidx[j + 2], s3 = eidx[j + 3];
        if (act) {
            uint v0 = *reinterpret_cast<const uint*>(xb + (size_t)s0 * DIN + l * 2);
            uint v1 = *reinterpret_cast<const uint*>(xb + (size_t)s1 * DIN + l * 2);
            uint v2 = *reinterpret_cast<const uint*>(xb + (size_t)s2 * DIN + l * 2);
            uint v3 = *reinterpret_cast<const uint*>(xb + (size_t)s3 * DIN + l * 2);
            a0 += bf2f(v0 & 0xffffu) + bf2f(v1 & 0xffffu) + bf2f(v2 & 0xffffu) + bf2f(v3 & 0xffffu);
            a1 += bf2f(v0 >> 16) + bf2f(v1 >> 16) + bf2f(v2 >> 16) + bf2f(v3 >> 16);
        }
    }
    for (; j < end; ++j) {
        int s0 = eidx[j];
        if (act) {
            uint v0 = *reinterpret_cast<const uint*>(xb + (size_t)s0 * DIN + l * 2);
            a0 += bf2f(v0 & 0xffffu);
            a1 += bf2f(v0 >> 16);
        }
    }
    float inv = 1.0f / fmaxf((float)(end - beg), 1.0f);
    if (act) {
        uint o = (uint)f2bf(a0 * inv) | ((uint)f2bf(a1 * inv) << 16);
        *reinterpret_cast<uint*>(out + (size_t)node * DIN + l * 2) = o;
    }
}

__global__ __launch_bounds__(256)
void agg100_f(const float* __restrict__ x, const int* __restrict__ rp,
              const int* __restrict__ eidx, ushort* __restrict__ out, int nNodes) {
    int node = blockIdx.x * 4 + (threadIdx.x >> 6);
    if (node >= nNodes) return;
    int l = threadIdx.x & 63;
    bool act = l < 50;
    int beg = rp[node], end = rp[node + 1];
    float a0 = 0.f, a1 = 0.f;
    int j = beg;
    for (; j + 1 < end; j += 2) {
        int s0 = eidx[j], s1 = eidx[j + 1];
        if (act) {
            float2 v0 = *reinterpret_cast<const float2*>(x + (size_t)s0 * DIN + l * 2);
            float2 v1 = *reinterpret_cast<const float2*>(x + (size_t)s1 * DIN + l * 2);
            a0 += v0.x + v1.x;
            a1 += v0.y + v1.y;
        }
    }
    if (j < end) {
        int s0 = eidx[j];
        if (act) {
            float2 v0 = *reinterpret_cast<const float2*>(x + (size_t)s0 * DIN + l * 2);
            a0 += v0.x; a1 += v0.y;
        }
    }
    float inv = 1.0f / fmaxf((float)(end - beg), 1.0f);
    if (act) {
        uint o = (uint)f2bf(a0 * inv) | ((uint)f2bf(a1 * inv) << 16);
        *reinterpret_cast<uint*>(out + (size_t)node * DIN + l * 2) = o;
    }
}

__global__ __launch_bounds__(256)
void agg256_b(const ushort* __restrict__ h, const int* __restrict__ rp,
              const int* __restrict__ eidx, ushort* __restrict__ out, int nNodes) {
    int node = blockIdx.x * 4 + (threadIdx.x >> 6);
    if (node >= nNodes) return;
    int l = threadIdx.x & 63;
    int beg = rp[node], end = rp[node + 1];
    float a0 = 0.f, a1 = 0.f, a2 = 0.f, a3 = 0.f;
    int j = beg;
    for (; j + 3 < end; j += 4) {
        int s0 = eidx[j], s1 = eidx[j + 1], s2 = eidx[j + 2], s3 = eidx[j + 3];
        uint2 v0 = *reinterpret_cast<const uint2*>(h + (size_t)s0 * DH + l * 4);
        uint2 v1 = *reinterpret_cast<const uint2*>(h + (size_t)s1 * DH + l * 4);
        uint2 v2 = *reinterpret_cast<const uint2*>(h + (size_t)s2 * DH + l * 4);
        uint2 v3 = *reinterpret_cast<const uint2*>(h + (size_t)s3 * DH + l * 4);
        a0 += bf2f(v0.x & 0xffffu) + bf2f(v1.x & 0xffffu) + bf2f(v2.x & 0xffffu) + bf2f(v3.x & 0xffffu);
        a1 += bf2f(v0.x >> 16)     + bf2f(v1.x >> 16)     + bf2f(v2.x >> 16)     + bf2f(v3.x >> 16);
        a2 += bf2f(v0.y & 0xffffu) + bf2f(v1.y & 0xffffu) + bf2f(v2.y & 0xffffu) + bf2f(v3.y & 0xffffu);
        a3 += bf2f(v0.y >> 16)     + bf2f(v1.y >> 16)     + bf2f(v2.y >> 16)     + bf2f(v3.y >> 16);
    }
    for (; j < end; ++j) {
        int s0 = eidx[j];
        uint2 v0 = *reinterpret_cast<const uint2*>(h + (size_t)s0 * DH + l * 4);
        a0 += bf2f(v0.x & 0xffffu);
        a1 += bf2f(v0.x >> 16);
        a2 += bf2f(v0.y & 0xffffu);
        a3 += bf2f(v0.y >> 16);
    }
    float inv = 1.0f / fmaxf((float)(end - beg), 1.0f);
    uint2 o;
    o.x = (uint)f2bf(a0 * inv) | ((uint)f2bf(a1 * inv) << 16);
    o.y = (uint)f2bf(a2 * inv) | ((uint)f2bf(a3 * inv) << 16);
    *reinterpret_cast<uint2*>(out + (size_t)node * DH + l * 4) = o;
}

// ================= dual MFMA GEMM ===========================================
template <int RELU, int OUTBF>
__global__ __launch_bounds__(256)
void gemm_dual(const ushort* __restrict__ A1, int K1, int S1, int str1,
               const ushort* __restrict__ A2, int K2, int S2, int str2,
               const ushort* __restrict__ B1p, const ushort* __restrict__ B2p,
               const float* __restrict__ bias, void* __restrict__ Cv,
               int M, int N, int NB, int NBW, int Cstride) {
    __shared__ ushort At[2][2048];

    const int tid = threadIdx.x;
    const int w = tid >> 6;
    const int l = tid & 63;
    const int m0 = blockIdx.x * 64;
    const int S = S1 + S2;

    f32x4 acc[4][4];
    #pragma unroll
    for (int m = 0; m < 4; ++m)
        #pragma unroll
        for (int i = 0; i < 4; ++i)
            acc[m][i] = f32x4{0.f, 0.f, 0.f, 0.f};

    auto stage = [&](int s, int buf) {
        const ushort* A; int str, Keff, ks;
        if (s < S1) { A = A1; str = str1; Keff = K1; ks = s; }
        else        { A = A2; str = str2; Keff = K2; ks = s - S1; }
        int r  = tid >> 2;
        int kc = tid & 3;
        int row = m0 + r;
        int k = ks * 32 + (kc << 3);
        U16B v;
        v.u4.x = v.u4.y = v.u4.z = v.u4.w = 0u;
        if (row < M && k < Keff) {
            const ushort* p = A + (size_t)row * str + k;
            v.u2[0] = *reinterpret_cast<const uint2*>(p);
            v.u2[1] = *reinterpret_cast<const uint2*>(p + 4);
            if (k + 8 > Keff) {
                #pragma unroll
                for (int j = 0; j < 8; ++j)
                    if (k + j >= Keff) v.us[j] = 0;
            }
        }
        int slot = ((r >> 4) << 6) | (r & 15) | (kc << 4);
        *reinterpret_cast<bhalf8*>(&At[buf][slot * 8]) = v.s8;
    };

    stage(0, 0);
    __syncthreads();

    for (int s = 0; s < S; ++s) {
        int buf = s & 1;
        if (s + 1 < S) stage(s + 1, buf ^ 1);

        const ushort* Bp; int ks;
        if (s < S1) { Bp = B1p; ks = s; }
        else        { Bp = B2p; ks = s - S1; }

        bhalf8 a[4];
        #pragma unroll
        for (int m = 0; m < 4; ++m)
            a[m] = *reinterpret_cast<bhalf8*>(&At[buf][((m << 6) | l) * 8]);

        #pragma unroll
        for (int i = 0; i < 4; ++i) {
            if (i < NBW) {
                int c = w * NBW + i;
                if (c < NB) {
                    bhalf8 b = *reinterpret_cast<const bhalf8*>(
                        Bp + ((size_t)(ks * NB + c) * 64 + l) * 8);
                    #pragma unroll
                    for (int m = 0; m < 4; ++m)
                        acc[m][i] = __builtin_amdgcn_mfma_f32_16x16x32_bf16(
                            a[m], b, acc[m][i], 0, 0, 0);
                }
            }
        }
        __syncthreads();
    }

    #pragma unroll
    for (int i = 0; i < 4; ++i) {
        if (i >= NBW) continue;
        int c = w * NBW + i;
        if (c >= NB) continue;
        int col = (c << 4) | (l & 15);
        if (col >= N) continue;
        float bb = bias[col];
        #pragma unroll
        for (int m = 0; m < 4; ++m) {
            #pragma unroll
            for (int e = 0; e < 4; ++e) {
                int row = m0 + (m << 4) + ((l >> 4) << 2) + e;
                if (row < M) {
                    float v = acc[m][i][e] + bb;
                    if (RELU) v = fmaxf(v, 0.0f);
                    if (OUTBF)
                        ((ushort*)Cv)[(size_t)row * Cstride + col] = f2bf(v);
                    else
                        ((float*)Cv)[(size_t)row * Cstride + col] = v;
                }
            }
        }
    }
}

// ================= log_softmax over 47 classes ==============================
__global__ void log_softmax_47(const float* __restrict__ z, float* __restrict__ out) {
    int row = blockIdx.x;
    int lane = threadIdx.x;
    float v = (lane < DOUT) ? z[(size_t)row * DOUT + lane] : -INFINITY;
    float m = v;
    #pragma unroll
    for (int off = 32; off; off >>= 1) m = fmaxf(m, __shfl_xor(m, off));
    float e = (lane < DOUT) ? expf(v - m) : 0.0f;
    float s = e;
    #pragma unroll
    for (int off = 32; off; off >>= 1) s += __shfl_xor(s, off);
    if (lane < DOUT) out[(size_t)row * DOUT + lane] = v - m - logf(s);
}

// ================= launch ====================================================
extern "C" void kernel_launch(void* const* d_in, const int* in_sizes, int n_in,
                              void* d_out, int out_size, void* d_ws, size_t ws_size,
                              hipStream_t stream) {
    const float* x   = (const float*)d_in[0];
    const int* e0s   = (const int*)d_in[1];
    const int* e0d   = (const int*)d_in[2];
    const int* e1s   = (const int*)d_in[3];
    const int* e1d   = (const int*)d_in[4];
    const int* e2s   = (const int*)d_in[5];
    const int* e2d   = (const int*)d_in[6];
    const float* Wl0 = (const float*)d_in[7];
    const float* Wr0 = (const float*)d_in[8];
    const float* b0  = (const float*)d_in[9];
    const float* Wl1 = (const float*)d_in[10];
    const float* Wr1 = (const float*)d_in[11];
    const float* b1  = (const float*)d_in[12];
    const float* Wl2 = (const float*)d_in[13];
    const float* Wr2 = (const float*)d_in[14];
    const float* b2  = (const float*)d_in[15];

    char* ws = (char*)d_ws;
    size_t off = 0;
    auto alloc = [&](size_t bytes) -> void* {
        void* p = ws + off;
        off += (bytes + 255) & ~(size_t)255;
        return p;
    };

    ushort* agg0b = (ushort*)alloc((size_t)NN1 * DIN * 2);
    ushort* h1    = (ushort*)alloc((size_t)NN1 * DH * 2);
    ushort* agg1b = (ushort*)alloc((size_t)NN2 * DH * 2);
    ushort* h2    = (ushort*)alloc((size_t)NN2 * DH * 2);
    ushort* agg2b = (ushort*)alloc((size_t)NN3 * DH * 2);
    float*  z     = (float*)alloc((size_t)NN3 * DOUT * 4);

    ushort* Bp0l = (ushort*)alloc((size_t)4 * 16 * 64 * 8 * 2);
    ushort* Bp0r = (ushort*)alloc((size_t)4 * 16 * 64 * 8 * 2);
    ushort* Bp1l = (ushort*)alloc((size_t)8 * 16 * 64 * 8 * 2);
    ushort* Bp1r = (ushort*)alloc((size_t)8 * 16 * 64 * 8 * 2);
    ushort* Bp2l = (ushort*)alloc((size_t)8 * 3 * 64 * 8 * 2);
    ushort* Bp2r = (ushort*)alloc((size_t)8 * 3 * 64 * 8 * 2);

    int* cntp   = (int*)alloc((size_t)NG * NTOT * 4);      // partitioned counters (31.8 MB)
    int* cntAll = (int*)alloc((size_t)NTOT * 4);           // combined counts
    int* pos0   = (int*)alloc((size_t)EE0 * 4);
    int* pos1   = (int*)alloc((size_t)EE1 * 4);
    int* pos2   = (int*)alloc((size_t)EE2 * 4);
    int* rp0    = (int*)alloc((size_t)(NN1 + 1) * 4);
    int* eidx0  = (int*)alloc((size_t)EE0 * 4);
    int* rp1    = (int*)alloc((size_t)(NN2 + 1) * 4);
    int* eidx1  = (int*)alloc((size_t)EE1 * 4);
    int* rp2    = (int*)alloc((size_t)(NN3 + 1) * 4);
    int* eidx2  = (int*)alloc((size_t)EE2 * 4);
    int* part   = (int*)alloc(256 * 4);

    size_t fullNeed = (size_t)NN0 * DIN * 2 + 4096;
    bool big = (ws_size - off) >= fullNeed;
    int xRows = big ? NN0 : NN1;
    ushort* xb = (ushort*)alloc((size_t)xRows * DIN * 2 + 256);

    // ---- K1: zero partitioned counters; hist(+rank) + conv + pack ----
    hipMemsetAsync(cntp, 0, (size_t)NG * NTOT * 4, stream);
    {
        long long n4 = (long long)xRows * DIN / 4;
        hist_conv<<<HBE + CONVBLK + PACKBLK, 256, 0, stream>>>(
            e0d, e1d, e2d, cntp, pos0, pos1, pos2, x, xb, n4,
            Wl0, Wr0, Wl1, Wr1, Wl2, Wr2,
            Bp0l, Bp0r, Bp1l, Bp1r, Bp2l, Bp2r);
    }

    // ---- K2: in-place partition scan + CSR scans ----
    combine_parts<<<(NTOT + 255) / 256, 256, 0, stream>>>(cntp, cntAll);
    scan1f<<<NBT, 256, 0, stream>>>(cntAll, part);
    scan2f<<<1, 128, 0, stream>>>(part);
    scan3f<<<NBT, 256, 0, stream>>>(cntAll, part, rp0, rp1, rp2);

    // ---- K3: atomic-free placement ----
    place_all<<<HBE, 256, 0, stream>>>(e0s, e0d, e1s, e1d, e2s, e2d,
                                       pos0, pos1, pos2, cntp,
                                       rp0, rp1, rp2, eidx0, eidx1, eidx2);

    // ---- layer 0 ----
    if (big)
        agg100_b<<<(NN1 + 3) / 4, 256, 0, stream>>>(xb, rp0, eidx0, agg0b, NN1);
    else
        agg100_f<<<(NN1 + 3) / 4, 256, 0, stream>>>(x, rp0, eidx0, agg0b, NN1);
    gemm_dual<1, 1><<<(NN1 + 63) / 64, 256, 0, stream>>>(
        agg0b, DIN, 4, DIN, xb, DIN, 4, DIN, Bp0l, Bp0r, b0, h1,
        NN1, DH, 16, 4, DH);

    // ---- layer 1 ----
    agg256_b<<<(NN2 + 3) / 4, 256, 0, stream>>>(h1, rp1, eidx1, agg1b, NN2);
    gemm_dual<1, 1><<<(NN2 + 63) / 64, 256, 0, stream>>>(
        agg1b, DH, 8, DH, h1, DH, 8, DH, Bp1l, Bp1r, b1, h2,
        NN2, DH, 16, 4, DH);

    // ---- layer 2 ----
    agg256_b<<<(NN3 + 3) / 4, 256, 0, stream>>>(h2, rp2, eidx2, agg2b, NN3);
    gemm_dual<0, 0><<<(NN3 + 63) / 64, 256, 0, stream>>>(
        agg2b, DH, 8, DH, h2, DH, 8, DH, Bp2l, Bp2r, b2, z,
        NN3, DOUT, 3, 1, DOUT);

    // ---- log_softmax ----
    log_softmax_47<<<NN3, 64, 0, stream>>>(z, (float*)d_out);
}

// Round 8
// 494.972 us; speedup vs baseline: 1.0042x; 1.0042x over previous
//
#include <hip/hip_runtime.h>

#define NN0 600000
#define NN1 100000
#define NN2 20000
#define NN3 4096
#define EE0 1500000
#define EE1 200000
#define EE2 40960
#define DIN 100
#define DH  256
#define DOUT 47
#define NTOT (NN1 + NN2 + NN3)   // 124096

// LDS-histogram geometry
#define RNG 16384                 // nodes per range (64 KB LDS of int counters)
#define CH0 32768                 // L0 edge chunk (g = e >> 15)
#define NC0 46                    // ceil(EE0/CH0)
#define R0  7                     // ceil(NN1/RNG)
#define CH1 16384                 // g = e >> 14
#define NC1 13
#define R1  2
#define CH2 8192                  // g = e >> 13
#define NC2 5
#define R2  1
#define HL0 (NC0 * R0)            // 322
#define HL1 (NC1 * R1)            // 26
#define HL2 (NC2 * R2)            // 5
#define HLT (HL0 + HL1 + HL2)     // 353
#define NGMAX 46

// fused scan geometry: ceil(N/1024) blocks per layer
#define NB0 98
#define NB1 20
#define NB2 4
#define NBT 122

// one-edge-per-thread block counts (256 thr/block) for placement
#define HB0 5860
#define HB1 782
#define HB2 160
#define HBE (HB0 + HB1 + HB2)
#define PACKBLK 108
#define CONVBLK 3072

typedef unsigned int uint;
typedef unsigned short ushort;
typedef __attribute__((ext_vector_type(8))) short bhalf8;
typedef __attribute__((ext_vector_type(4))) float f32x4;

union U16B {
    uint2  u2[2];
    uint4  u4;
    bhalf8 s8;
    ushort us[8];
};

__device__ __forceinline__ ushort f2bf(float f) {
    uint u = __float_as_uint(f);
    uint r = (u + 0x7FFFu + ((u >> 16) & 1u)) >> 16;
    return (ushort)r;
}
__device__ __forceinline__ float bf2f(uint bits16) {
    return __uint_as_float(bits16 << 16);
}

// ================= K1a: LDS histogram + rank assignment =====================
// Block = (layer, range r, chunk c). LDS counters for its 16384-node range;
// rank for each edge comes from LDS atomicAdd return (block-local, fast).
__global__ __launch_bounds__(256)
void hist_lds(const int* __restrict__ e0d, const int* __restrict__ e1d,
              const int* __restrict__ e2d, int* __restrict__ cntp,
              int* __restrict__ pos0, int* __restrict__ pos1,
              int* __restrict__ pos2) {
    __shared__ int lcnt[RNG];     // 64 KB
    int b = blockIdx.x, tid = threadIdx.x;
    const int* dstp; int E, CH, c, r, nbase, layerN;
    int* pos;
    if (b < HL0) {
        dstp = e0d; E = EE0; CH = CH0; c = b / R0; r = b % R0;
        nbase = 0; layerN = NN1; pos = pos0;
    } else if (b < HL0 + HL1) {
        int bb = b - HL0;
        dstp = e1d; E = EE1; CH = CH1; c = bb / R1; r = bb % R1;
        nbase = NN1; layerN = NN2; pos = pos1;
    } else {
        int bb = b - HL0 - HL1;
        dstp = e2d; E = EE2; CH = CH2; c = bb; r = 0;
        nbase = NN1 + NN2; layerN = NN3; pos = pos2;
    }
    for (int i = tid; i < RNG; i += 256) lcnt[i] = 0;
    __syncthreads();
    int rbase = r * RNG;
    long long ebase = (long long)c * CH;
    for (int i = tid; i < CH; i += 256) {
        int e = (int)(ebase + i);
        if (e < E) {
            int d = dstp[e];
            unsigned li = (unsigned)(d - rbase);
            if (li < RNG) pos[e] = atomicAdd(&lcnt[li], 1);
        }
    }
    __syncthreads();
    for (int i = tid; i < RNG; i += 256) {
        int node = rbase + i;
        if (node < layerN)
            cntp[(size_t)c * NTOT + nbase + node] = lcnt[i];
    }
}

// ================= K1b: x->bf16 conversion + weight pack ====================
__device__ __forceinline__ void pack_one(const float* B, int K, int N, int NB,
                                         ushort* out, int bid, int l) {
    int kstep = bid / NB;
    int c = bid % NB;
    U16B v;
    #pragma unroll
    for (int j = 0; j < 8; ++j) {
        int k = kstep * 32 + ((l >> 4) << 3) + j;
        int col = (c << 4) | (l & 15);
        float f = (k < K && col < N) ? B[(size_t)k * N + col] : 0.0f;
        v.us[j] = f2bf(f);
    }
    *reinterpret_cast<bhalf8*>(out + ((size_t)bid * 64 + l) * 8) = v.s8;
}

__global__ __launch_bounds__(256)
void conv_pack(const float* __restrict__ x, ushort* __restrict__ xb, long long n4,
               const float* __restrict__ Wl0, const float* __restrict__ Wr0,
               const float* __restrict__ Wl1, const float* __restrict__ Wr1,
               const float* __restrict__ Wl2, const float* __restrict__ Wr2,
               ushort* Bp0l, ushort* Bp0r, ushort* Bp1l, ushort* Bp1r,
               ushort* Bp2l, ushort* Bp2r) {
    int b = blockIdx.x;
    int tid = threadIdx.x;
    if (b < CONVBLK) {
        for (long long t = (long long)b * 256 + tid; t < n4;
             t += (long long)CONVBLK * 256) {
            float4 v = *reinterpret_cast<const float4*>(x + t * 4);
            uint2 o;
            o.x = (uint)f2bf(v.x) | ((uint)f2bf(v.y) << 16);
            o.y = (uint)f2bf(v.z) | ((uint)f2bf(v.w) << 16);
            *reinterpret_cast<uint2*>(xb + t * 4) = o;
        }
    } else {
        int bid = (b - CONVBLK) * 4 + (tid >> 6);
        int l = tid & 63;
        if (bid < 64)       pack_one(Wl0, DIN, DH,  16, Bp0l, bid,       l);
        else if (bid < 128) pack_one(Wr0, DIN, DH,  16, Bp0r, bid - 64,  l);
        else if (bid < 256) pack_one(Wl1, DH,  DH,  16, Bp1l, bid - 128, l);
        else if (bid < 384) pack_one(Wr1, DH,  DH,  16, Bp1r, bid - 256, l);
        else if (bid < 408) pack_one(Wl2, DH,  DOUT, 3, Bp2l, bid - 384, l);
        else                pack_one(Wr2, DH,  DOUT, 3, Bp2r, bid - 408, l);
    }
}

// ================= K2: in-place exclusive scan over groups ==================
// After this, cntp[g][i] = edges for node i in chunks < g; cntAll[i] = total.
__global__ __launch_bounds__(256)
void combine_parts(int* __restrict__ cntp, int* __restrict__ cntAll) {
    int i = blockIdx.x * 256 + threadIdx.x;
    if (i >= NTOT) return;
    int ng = (i < NN1) ? NC0 : (i < NN1 + NN2) ? NC1 : NC2;
    int run = 0;
    for (int g = 0; g < ng; ++g) {
        size_t idx = (size_t)g * NTOT + i;
        int v = cntp[idx];
        cntp[idx] = run;
        run += v;
    }
    cntAll[i] = run;
}

// ================= fused CSR scans ==========================================

__device__ __forceinline__ void layer_of(int b, int& lb, int& n, int& po, int& cb) {
    if (b < NB0)      { lb = b;        n = NN1; po = 0;         cb = 0; }
    else if (b < NB0 + NB1) { lb = b - NB0;  n = NN2; po = NB0; cb = NN1; }
    else              { lb = b - NB0 - NB1; n = NN3; po = NB0 + NB1; cb = NN1 + NN2; }
}

__global__ void scan1f(const int* __restrict__ cntAll, int* __restrict__ part) {
    int lb, n, po, cb;
    layer_of(blockIdx.x, lb, n, po, cb);
    __shared__ int s[256];
    int base = lb * 1024;
    int sum = 0;
    for (int i = threadIdx.x; i < 1024; i += 256) {
        int idx = base + i;
        sum += (idx < n) ? cntAll[cb + idx] : 0;
    }
    s[threadIdx.x] = sum;
    __syncthreads();
    for (int off = 128; off; off >>= 1) {
        if (threadIdx.x < off) s[threadIdx.x] += s[threadIdx.x + off];
        __syncthreads();
    }
    if (threadIdx.x == 0) part[po + lb] = s[0];
}

__global__ void scan2f(int* part) {
    __shared__ int s[128];
    int t = threadIdx.x;
    int seg = (t < NB0) ? 0 : (t < NB0 + NB1) ? 1 : (t < NBT) ? 2 : 3;
    int v = (t < NBT) ? part[t] : 0;
    s[t] = v;
    __syncthreads();
    for (int off = 1; off < 128; off <<= 1) {
        int add = 0;
        if (t >= off) {
            int u = t - off;
            int segu = (u < NB0) ? 0 : (u < NB0 + NB1) ? 1 : (u < NBT) ? 2 : 3;
            if (segu == seg) add = s[u];
        }
        __syncthreads();
        s[t] += add;
        __syncthreads();
    }
    if (t < NBT) part[t] = s[t] - v;
}

__global__ void scan3f(const int* __restrict__ cntAll, const int* __restrict__ part,
                       int* __restrict__ rp0, int* __restrict__ rp1,
                       int* __restrict__ rp2) {
    int lb, n, po, cb;
    layer_of(blockIdx.x, lb, n, po, cb);
    int* row_ptr;
    if (cb == 0)        row_ptr = rp0;
    else if (cb == NN1) row_ptr = rp1;
    else                row_ptr = rp2;

    __shared__ int s[256];
    int base = lb * 1024;
    int v[4];
    int sum = 0;
    #pragma unroll
    for (int j = 0; j < 4; ++j) {
        int idx = base + threadIdx.x * 4 + j;
        v[j] = (idx < n) ? cntAll[cb + idx] : 0;
        sum += v[j];
    }
    s[threadIdx.x] = sum;
    __syncthreads();
    for (int off = 1; off < 256; off <<= 1) {
        int t = (threadIdx.x >= off) ? s[threadIdx.x - off] : 0;
        __syncthreads();
        s[threadIdx.x] += t;
        __syncthreads();
    }
    int off0 = part[po + lb] + s[threadIdx.x] - sum;
    #pragma unroll
    for (int j = 0; j < 4; ++j) {
        int idx = base + threadIdx.x * 4 + j;
        if (idx < n) {
            row_ptr[idx] = off0;
            off0 += v[j];
            if (idx == n - 1) row_ptr[n] = off0;
        }
    }
}

// ================= K3: atomic-free placement ================================
__global__ __launch_bounds__(256)
void place_all(const int* __restrict__ e0s, const int* __restrict__ e0d,
               const int* __restrict__ e1s, const int* __restrict__ e1d,
               const int* __restrict__ e2s, const int* __restrict__ e2d,
               const int* __restrict__ pos0, const int* __restrict__ pos1,
               const int* __restrict__ pos2, const int* __restrict__ cntp,
               const int* __restrict__ rp0, const int* __restrict__ rp1,
               const int* __restrict__ rp2,
               int* __restrict__ eidx0, int* __restrict__ eidx1,
               int* __restrict__ eidx2) {
    int b = blockIdx.x;
    int tid = threadIdx.x;
    if (b < HB0) {
        int e = b * 256 + tid;
        if (e < EE0) {
            int d = e0d[e];
            int g = e >> 15;
            int p = rp0[d] + cntp[(size_t)g * NTOT + d] + pos0[e];
            eidx0[p] = e0s[e];
        }
    } else if (b < HB0 + HB1) {
        int e = (b - HB0) * 256 + tid;
        if (e < EE1) {
            int d = e1d[e];
            int g = e >> 14;
            int p = rp1[d] + cntp[(size_t)g * NTOT + NN1 + d] + pos1[e];
            eidx1[p] = e1s[e];
        }
    } else {
        int e = (b - HB0 - HB1) * 256 + tid;
        if (e < EE2) {
            int d = e2d[e];
            int g = e >> 13;
            int p = rp2[d] + cntp[(size_t)g * NTOT + NN1 + NN2 + d] + pos2[e];
            eidx2[p] = e2s[e];
        }
    }
}

// ================= pull aggregation (fp32 accum, bf16 out, mean folded) ======

__global__ __launch_bounds__(256)
void agg100_b(const ushort* __restrict__ xb, const int* __restrict__ rp,
              const int* __restrict__ eidx, ushort* __restrict__ out, int nNodes) {
    int node = blockIdx.x * 4 + (threadIdx.x >> 6);
    if (node >= nNodes) return;
    int l = threadIdx.x & 63;
    bool act = l < 50;
    int beg = rp[node], end = rp[node + 1];
    float a0 = 0.f, a1 = 0.f;
    int j = beg;
    for (; j + 3 < end; j += 4) {
        int s0 = eidx[j], s1 = eidx[j + 1], s2 = eidx[j + 2], s3 = eidx[j + 3];
        if (act) {
            uint v0 = *reinterpret_cast<const uint*>(xb + (size_t)s0 * DIN + l * 2);
            uint v1 = *reinterpret_cast<const uint*>(xb + (size_t)s1 * DIN + l * 2);
            uint v2 = *reinterpret_cast<const uint*>(xb + (size_t)s2 * DIN + l * 2);
            uint v3 = *reinterpret_cast<const uint*>(xb + (size_t)s3 * DIN + l * 2);
            a0 += bf2f(v0 & 0xffffu) + bf2f(v1 & 0xffffu) + bf2f(v2 & 0xffffu) + bf2f(v3 & 0xffffu);
            a1 += bf2f(v0 >> 16) + bf2f(v1 >> 16) + bf2f(v2 >> 16) + bf2f(v3 >> 16);
        }
    }
    for (; j < end; ++j) {
        int s0 = eidx[j];
        if (act) {
            uint v0 = *reinterpret_cast<const uint*>(xb + (size_t)s0 * DIN + l * 2);
            a0 += bf2f(v0 & 0xffffu);
            a1 += bf2f(v0 >> 16);
        }
    }
    float inv = 1.0f / fmaxf((float)(end - beg), 1.0f);
    if (act) {
        uint o = (uint)f2bf(a0 * inv) | ((uint)f2bf(a1 * inv) << 16);
        *reinterpret_cast<uint*>(out + (size_t)node * DIN + l * 2) = o;
    }
}

__global__ __launch_bounds__(256)
void agg100_f(const float* __restrict__ x, const int* __restrict__ rp,
              const int* __restrict__ eidx, ushort* __restrict__ out, int nNodes) {
    int node = blockIdx.x * 4 + (threadIdx.x >> 6);
    if (node >= nNodes) return;
    int l = threadIdx.x & 63;
    bool act = l < 50;
    int beg = rp[node], end = rp[node + 1];
    float a0 = 0.f, a1 = 0.f;
    int j = beg;
    for (; j + 1 < end; j += 2) {
        int s0 = eidx[j], s1 = eidx[j + 1];
        if (act) {
            float2 v0 = *reinterpret_cast<const float2*>(x + (size_t)s0 * DIN + l * 2);
            float2 v1 = *reinterpret_cast<const float2*>(x + (size_t)s1 * DIN + l * 2);
            a0 += v0.x + v1.x;
            a1 += v0.y + v1.y;
        }
    }
    if (j < end) {
        int s0 = eidx[j];
        if (act) {
            float2 v0 = *reinterpret_cast<const float2*>(x + (size_t)s0 * DIN + l * 2);
            a0 += v0.x; a1 += v0.y;
        }
    }
    float inv = 1.0f / fmaxf((float)(end - beg), 1.0f);
    if (act) {
        uint o = (uint)f2bf(a0 * inv) | ((uint)f2bf(a1 * inv) << 16);
        *reinterpret_cast<uint*>(out + (size_t)node * DIN + l * 2) = o;
    }
}

__global__ __launch_bounds__(256)
void agg256_b(const ushort* __restrict__ h, const int* __restrict__ rp,
              const int* __restrict__ eidx, ushort* __restrict__ out, int nNodes) {
    int node = blockIdx.x * 4 + (threadIdx.x >> 6);
    if (node >= nNodes) return;
    int l = threadIdx.x & 63;
    int beg = rp[node], end = rp[node + 1];
    float a0 = 0.f, a1 = 0.f, a2 = 0.f, a3 = 0.f;
    int j = beg;
    for (; j + 3 < end; j += 4) {
        int s0 = eidx[j], s1 = eidx[j + 1], s2 = eidx[j + 2], s3 = eidx[j + 3];
        uint2 v0 = *reinterpret_cast<const uint2*>(h + (size_t)s0 * DH + l * 4);
        uint2 v1 = *reinterpret_cast<const uint2*>(h + (size_t)s1 * DH + l * 4);
        uint2 v2 = *reinterpret_cast<const uint2*>(h + (size_t)s2 * DH + l * 4);
        uint2 v3 = *reinterpret_cast<const uint2*>(h + (size_t)s3 * DH + l * 4);
        a0 += bf2f(v0.x & 0xffffu) + bf2f(v1.x & 0xffffu) + bf2f(v2.x & 0xffffu) + bf2f(v3.x & 0xffffu);
        a1 += bf2f(v0.x >> 16)     + bf2f(v1.x >> 16)     + bf2f(v2.x >> 16)     + bf2f(v3.x >> 16);
        a2 += bf2f(v0.y & 0xffffu) + bf2f(v1.y & 0xffffu) + bf2f(v2.y & 0xffffu) + bf2f(v3.y & 0xffffu);
        a3 += bf2f(v0.y >> 16)     + bf2f(v1.y >> 16)     + bf2f(v2.y >> 16)     + bf2f(v3.y >> 16);
    }
    for (; j < end; ++j) {
        int s0 = eidx[j];
        uint2 v0 = *reinterpret_cast<const uint2*>(h + (size_t)s0 * DH + l * 4);
        a0 += bf2f(v0.x & 0xffffu);
        a1 += bf2f(v0.x >> 16);
        a2 += bf2f(v0.y & 0xffffu);
        a3 += bf2f(v0.y >> 16);
    }
    float inv = 1.0f / fmaxf((float)(end - beg), 1.0f);
    uint2 o;
    o.x = (uint)f2bf(a0 * inv) | ((uint)f2bf(a1 * inv) << 16);
    o.y = (uint)f2bf(a2 * inv) | ((uint)f2bf(a3 * inv) << 16);
    *reinterpret_cast<uint2*>(out + (size_t)node * DH + l * 4) = o;
}

// ================= dual MFMA GEMM ===========================================
template <int RELU, int OUTBF>
__global__ __launch_bounds__(256)
void gemm_dual(const ushort* __restrict__ A1, int K1, int S1, int str1,
               const ushort* __restrict__ A2, int K2, int S2, int str2,
               const ushort* __restrict__ B1p, const ushort* __restrict__ B2p,
               const float* __restrict__ bias, void* __restrict__ Cv,
               int M, int N, int NB, int NBW, int Cstride) {
    __shared__ ushort At[2][2048];

    const int tid = threadIdx.x;
    const int w = tid >> 6;
    const int l = tid & 63;
    const int m0 = blockIdx.x * 64;
    const int S = S1 + S2;

    f32x4 acc[4][4];
    #pragma unroll
    for (int m = 0; m < 4; ++m)
        #pragma unroll
        for (int i = 0; i < 4; ++i)
            acc[m][i] = f32x4{0.f, 0.f, 0.f, 0.f};

    auto stage = [&](int s, int buf) {
        const ushort* A; int str, Keff, ks;
        if (s < S1) { A = A1; str = str1; Keff = K1; ks = s; }
        else        { A = A2; str = str2; Keff = K2; ks = s - S1; }
        int r  = tid >> 2;
        int kc = tid & 3;
        int row = m0 + r;
        int k = ks * 32 + (kc << 3);
        U16B v;
        v.u4.x = v.u4.y = v.u4.z = v.u4.w = 0u;
        if (row < M && k < Keff) {
            const ushort* p = A + (size_t)row * str + k;
            v.u2[0] = *reinterpret_cast<const uint2*>(p);
            v.u2[1] = *reinterpret_cast<const uint2*>(p + 4);
            if (k + 8 > Keff) {
                #pragma unroll
                for (int j = 0; j < 8; ++j)
                    if (k + j >= Keff) v.us[j] = 0;
            }
        }
        int slot = ((r >> 4) << 6) | (r & 15) | (kc << 4);
        *reinterpret_cast<bhalf8*>(&At[buf][slot * 8]) = v.s8;
    };

    stage(0, 0);
    __syncthreads();

    for (int s = 0; s < S; ++s) {
        int buf = s & 1;
        if (s + 1 < S) stage(s + 1, buf ^ 1);

        const ushort* Bp; int ks;
        if (s < S1) { Bp = B1p; ks = s; }
        else        { Bp = B2p; ks = s - S1; }

        bhalf8 a[4];
        #pragma unroll
        for (int m = 0; m < 4; ++m)
            a[m] = *reinterpret_cast<bhalf8*>(&At[buf][((m << 6) | l) * 8]);

        #pragma unroll
        for (int i = 0; i < 4; ++i) {
            if (i < NBW) {
                int c = w * NBW + i;
                if (c < NB) {
                    bhalf8 b = *reinterpret_cast<const bhalf8*>(
                        Bp + ((size_t)(ks * NB + c) * 64 + l) * 8);
                    #pragma unroll
                    for (int m = 0; m < 4; ++m)
                        acc[m][i] = __builtin_amdgcn_mfma_f32_16x16x32_bf16(
                            a[m], b, acc[m][i], 0, 0, 0);
                }
            }
        }
        __syncthreads();
    }

    #pragma unroll
    for (int i = 0; i < 4; ++i) {
        if (i >= NBW) continue;
        int c = w * NBW + i;
        if (c >= NB) continue;
        int col = (c << 4) | (l & 15);
        if (col >= N) continue;
        float bb = bias[col];
        #pragma unroll
        for (int m = 0; m < 4; ++m) {
            #pragma unroll
            for (int e = 0; e < 4; ++e) {
                int row = m0 + (m << 4) + ((l >> 4) << 2) + e;
                if (row < M) {
                    float v = acc[m][i][e] + bb;
                    if (RELU) v = fmaxf(v, 0.0f);
                    if (OUTBF)
                        ((ushort*)Cv)[(size_t)row * Cstride + col] = f2bf(v);
                    else
                        ((float*)Cv)[(size_t)row * Cstride + col] = v;
                }
            }
        }
    }
}

// ================= log_softmax over 47 classes ==============================
__global__ void log_softmax_47(const float* __restrict__ z, float* __restrict__ out) {
    int row = blockIdx.x;
    int lane = threadIdx.x;
    float v = (lane < DOUT) ? z[(size_t)row * DOUT + lane] : -INFINITY;
    float m = v;
    #pragma unroll
    for (int off = 32; off; off >>= 1) m = fmaxf(m, __shfl_xor(m, off));
    float e = (lane < DOUT) ? expf(v - m) : 0.0f;
    float s = e;
    #pragma unroll
    for (int off = 32; off; off >>= 1) s += __shfl_xor(s, off);
    if (lane < DOUT) out[(size_t)row * DOUT + lane] = v - m - logf(s);
}

// ================= launch ====================================================
extern "C" void kernel_launch(void* const* d_in, const int* in_sizes, int n_in,
                              void* d_out, int out_size, void* d_ws, size_t ws_size,
                              hipStream_t stream) {
    const float* x   = (const float*)d_in[0];
    const int* e0s   = (const int*)d_in[1];
    const int* e0d   = (const int*)d_in[2];
    const int* e1s   = (const int*)d_in[3];
    const int* e1d   = (const int*)d_in[4];
    const int* e2s   = (const int*)d_in[5];
    const int* e2d   = (const int*)d_in[6];
    const float* Wl0 = (const float*)d_in[7];
    const float* Wr0 = (const float*)d_in[8];
    const float* b0  = (const float*)d_in[9];
    const float* Wl1 = (const float*)d_in[10];
    const float* Wr1 = (const float*)d_in[11];
    const float* b1  = (const float*)d_in[12];
    const float* Wl2 = (const float*)d_in[13];
    const float* Wr2 = (const float*)d_in[14];
    const float* b2  = (const float*)d_in[15];

    char* ws = (char*)d_ws;
    size_t off = 0;
    auto alloc = [&](size_t bytes) -> void* {
        void* p = ws + off;
        off += (bytes + 255) & ~(size_t)255;
        return p;
    };

    ushort* agg0b = (ushort*)alloc((size_t)NN1 * DIN * 2);
    ushort* h1    = (ushort*)alloc((size_t)NN1 * DH * 2);
    ushort* agg1b = (ushort*)alloc((size_t)NN2 * DH * 2);
    ushort* h2    = (ushort*)alloc((size_t)NN2 * DH * 2);
    ushort* agg2b = (ushort*)alloc((size_t)NN3 * DH * 2);
    float*  z     = (float*)alloc((size_t)NN3 * DOUT * 4);

    ushort* Bp0l = (ushort*)alloc((size_t)4 * 16 * 64 * 8 * 2);
    ushort* Bp0r = (ushort*)alloc((size_t)4 * 16 * 64 * 8 * 2);
    ushort* Bp1l = (ushort*)alloc((size_t)8 * 16 * 64 * 8 * 2);
    ushort* Bp1r = (ushort*)alloc((size_t)8 * 16 * 64 * 8 * 2);
    ushort* Bp2l = (ushort*)alloc((size_t)8 * 3 * 64 * 8 * 2);
    ushort* Bp2r = (ushort*)alloc((size_t)8 * 3 * 64 * 8 * 2);

    int* cntp   = (int*)alloc((size_t)NGMAX * NTOT * 4);   // 22.8 MB, no memset needed
    int* cntAll = (int*)alloc((size_t)NTOT * 4);
    int* pos0   = (int*)alloc((size_t)EE0 * 4);
    int* pos1   = (int*)alloc((size_t)EE1 * 4);
    int* pos2   = (int*)alloc((size_t)EE2 * 4);
    int* rp0    = (int*)alloc((size_t)(NN1 + 1) * 4);
    int* eidx0  = (int*)alloc((size_t)EE0 * 4);
    int* rp1    = (int*)alloc((size_t)(NN2 + 1) * 4);
    int* eidx1  = (int*)alloc((size_t)EE1 * 4);
    int* rp2    = (int*)alloc((size_t)(NN3 + 1) * 4);
    int* eidx2  = (int*)alloc((size_t)EE2 * 4);
    int* part   = (int*)alloc(256 * 4);

    size_t fullNeed = (size_t)NN0 * DIN * 2 + 4096;
    bool big = (ws_size - off) >= fullNeed;
    int xRows = big ? NN0 : NN1;
    ushort* xb = (ushort*)alloc((size_t)xRows * DIN * 2 + 256);

    // ---- K1a: LDS histogram + rank (no global atomics) ----
    hist_lds<<<HLT, 256, 0, stream>>>(e0d, e1d, e2d, cntp, pos0, pos1, pos2);

    // ---- K1b: x->bf16 + weight pack ----
    {
        long long n4 = (long long)xRows * DIN / 4;
        conv_pack<<<CONVBLK + PACKBLK, 256, 0, stream>>>(
            x, xb, n4, Wl0, Wr0, Wl1, Wr1, Wl2, Wr2,
            Bp0l, Bp0r, Bp1l, Bp1r, Bp2l, Bp2r);
    }

    // ---- K2: group scan + CSR scans ----
    combine_parts<<<(NTOT + 255) / 256, 256, 0, stream>>>(cntp, cntAll);
    scan1f<<<NBT, 256, 0, stream>>>(cntAll, part);
    scan2f<<<1, 128, 0, stream>>>(part);
    scan3f<<<NBT, 256, 0, stream>>>(cntAll, part, rp0, rp1, rp2);

    // ---- K3: atomic-free placement ----
    place_all<<<HBE, 256, 0, stream>>>(e0s, e0d, e1s, e1d, e2s, e2d,
                                       pos0, pos1, pos2, cntp,
                                       rp0, rp1, rp2, eidx0, eidx1, eidx2);

    // ---- layer 0 ----
    if (big)
        agg100_b<<<(NN1 + 3) / 4, 256, 0, stream>>>(xb, rp0, eidx0, agg0b, NN1);
    else
        agg100_f<<<(NN1 + 3) / 4, 256, 0, stream>>>(x, rp0, eidx0, agg0b, NN1);
    gemm_dual<1, 1><<<(NN1 + 63) / 64, 256, 0, stream>>>(
        agg0b, DIN, 4, DIN, xb, DIN, 4, DIN, Bp0l, Bp0r, b0, h1,
        NN1, DH, 16, 4, DH);

    // ---- layer 1 ----
    agg256_b<<<(NN2 + 3) / 4, 256, 0, stream>>>(h1, rp1, eidx1, agg1b, NN2);
    gemm_dual<1, 1><<<(NN2 + 63) / 64, 256, 0, stream>>>(
        agg1b, DH, 8, DH, h1, DH, 8, DH, Bp1l, Bp1r, b1, h2,
        NN2, DH, 16, 4, DH);

    // ---- layer 2 ----
    agg256_b<<<(NN3 + 3) / 4, 256, 0, stream>>>(h2, rp2, eidx2, agg2b, NN3);
    gemm_dual<0, 0><<<(NN3 + 63) / 64, 256, 0, stream>>>(
        agg2b, DH, 8, DH, h2, DH, 8, DH, Bp2l, Bp2r, b2, z,
        NN3, DOUT, 3, 1, DOUT);

    // ---- log_softmax ----
    log_softmax_47<<<NN3, 64, 0, stream>>>(z, (float*)d_out);
}

// Round 9
// 413.841 us; speedup vs baseline: 1.2011x; 1.1960x over previous
//
#include <hip/hip_runtime.h>

#define NN0 600000
#define NN1 100000
#define NN2 20000
#define NN3 4096
#define EE0 1500000
#define EE1 200000
#define EE2 40960
#define DIN 100
#define DH  256
#define DOUT 47
#define NTOT (NN1 + NN2 + NN3)   // 124096

// LDS-histogram geometry (1024-thread blocks)
#define RNG 16384                 // nodes per range (64 KB LDS of int counters)
#define CH0 32768                 // L0 edge chunk (g = e >> 15)
#define NC0 46                    // ceil(EE0/CH0)
#define R0  7                     // ceil(NN1/RNG)
#define CH1 16384                 // g = e >> 14
#define NC1 13
#define R1  2
#define CH2 8192                  // g = e >> 13
#define NC2 5
#define R2  1
#define HL0 (NC0 * R0)            // 322
#define HL1 (NC1 * R1)            // 26
#define HL2 (NC2 * R2)            // 5
#define HLT (HL0 + HL1 + HL2)     // 353
#define NGMAX 46

// fused scan geometry: ceil(N/1024) blocks per layer
#define NB0 98
#define NB1 20
#define NB2 4
#define NBT 122

// one-edge-per-thread block counts (256 thr/block) for placement
#define HB0 5860
#define HB1 782
#define HB2 160
#define HBE (HB0 + HB1 + HB2)

typedef unsigned int uint;
typedef unsigned short ushort;
typedef __attribute__((ext_vector_type(8))) short bhalf8;
typedef __attribute__((ext_vector_type(4))) float f32x4;

union U16B {
    uint2  u2[2];
    uint4  u4;
    bhalf8 s8;
    ushort us[8];
};

__device__ __forceinline__ ushort f2bf(float f) {
    uint u = __float_as_uint(f);
    uint r = (u + 0x7FFFu + ((u >> 16) & 1u)) >> 16;
    return (ushort)r;
}
__device__ __forceinline__ float bf2f(uint bits16) {
    return __uint_as_float(bits16 << 16);
}

// ================= K1a: LDS histogram + rank assignment (1024 thr) ==========
__global__ __launch_bounds__(1024)
void hist_lds(const int* __restrict__ e0d, const int* __restrict__ e1d,
              const int* __restrict__ e2d, int* __restrict__ cntp,
              int* __restrict__ pos0, int* __restrict__ pos1,
              int* __restrict__ pos2) {
    __shared__ int lcnt[RNG];     // 64 KB
    int b = blockIdx.x, tid = threadIdx.x;
    const int* dstp; int E, CH, c, r, nbase, layerN;
    int* pos;
    if (b < HL0) {
        dstp = e0d; E = EE0; CH = CH0; c = b / R0; r = b % R0;
        nbase = 0; layerN = NN1; pos = pos0;
    } else if (b < HL0 + HL1) {
        int bb = b - HL0;
        dstp = e1d; E = EE1; CH = CH1; c = bb / R1; r = bb % R1;
        nbase = NN1; layerN = NN2; pos = pos1;
    } else {
        int bb = b - HL0 - HL1;
        dstp = e2d; E = EE2; CH = CH2; c = bb; r = 0;
        nbase = NN1 + NN2; layerN = NN3; pos = pos2;
    }
    for (int i = tid; i < RNG; i += 1024) lcnt[i] = 0;
    __syncthreads();
    int rbase = r * RNG;
    long long ebase = (long long)c * CH;
    for (int i = tid; i < CH; i += 1024) {
        int e = (int)(ebase + i);
        if (e < E) {
            int d = dstp[e];
            unsigned li = (unsigned)(d - rbase);
            if (li < RNG) pos[e] = atomicAdd(&lcnt[li], 1);
        }
    }
    __syncthreads();
    for (int i = tid; i < RNG; i += 1024) {
        int node = rbase + i;
        if (node < layerN)
            cntp[(size_t)c * NTOT + nbase + node] = lcnt[i];
    }
}

// ================= K1b: weight pack =========================================
__device__ __forceinline__ void pack_one(const float* B, int K, int N, int NB,
                                         ushort* out, int bid, int l) {
    int kstep = bid / NB;
    int c = bid % NB;
    U16B v;
    #pragma unroll
    for (int j = 0; j < 8; ++j) {
        int k = kstep * 32 + ((l >> 4) << 3) + j;
        int col = (c << 4) | (l & 15);
        float f = (k < K && col < N) ? B[(size_t)k * N + col] : 0.0f;
        v.us[j] = f2bf(f);
    }
    *reinterpret_cast<bhalf8*>(out + ((size_t)bid * 64 + l) * 8) = v.s8;
}

__global__ __launch_bounds__(256)
void pack_all(const float* __restrict__ Wl0, const float* __restrict__ Wr0,
              const float* __restrict__ Wl1, const float* __restrict__ Wr1,
              const float* __restrict__ Wl2, const float* __restrict__ Wr2,
              ushort* Bp0l, ushort* Bp0r, ushort* Bp1l, ushort* Bp1r,
              ushort* Bp2l, ushort* Bp2r) {
    int bid = blockIdx.x * 4 + (threadIdx.x >> 6);
    int l = threadIdx.x & 63;
    if (bid < 64)       pack_one(Wl0, DIN, DH,  16, Bp0l, bid,       l);
    else if (bid < 128) pack_one(Wr0, DIN, DH,  16, Bp0r, bid - 64,  l);
    else if (bid < 256) pack_one(Wl1, DH,  DH,  16, Bp1l, bid - 128, l);
    else if (bid < 384) pack_one(Wr1, DH,  DH,  16, Bp1r, bid - 256, l);
    else if (bid < 408) pack_one(Wl2, DH,  DOUT, 3, Bp2l, bid - 384, l);
    else if (bid < 432) pack_one(Wr2, DH,  DOUT, 3, Bp2r, bid - 408, l);
}

// ================= K2: in-place exclusive scan over groups ==================
__global__ __launch_bounds__(256)
void combine_parts(int* __restrict__ cntp, int* __restrict__ cntAll) {
    int i = blockIdx.x * 256 + threadIdx.x;
    if (i >= NTOT) return;
    int ng = (i < NN1) ? NC0 : (i < NN1 + NN2) ? NC1 : NC2;
    int run = 0;
    for (int g = 0; g < ng; ++g) {
        size_t idx = (size_t)g * NTOT + i;
        int v = cntp[idx];
        cntp[idx] = run;
        run += v;
    }
    cntAll[i] = run;
}

// ================= fused CSR scans ==========================================

__device__ __forceinline__ void layer_of(int b, int& lb, int& n, int& po, int& cb) {
    if (b < NB0)      { lb = b;        n = NN1; po = 0;         cb = 0; }
    else if (b < NB0 + NB1) { lb = b - NB0;  n = NN2; po = NB0; cb = NN1; }
    else              { lb = b - NB0 - NB1; n = NN3; po = NB0 + NB1; cb = NN1 + NN2; }
}

__global__ void scan1f(const int* __restrict__ cntAll, int* __restrict__ part) {
    int lb, n, po, cb;
    layer_of(blockIdx.x, lb, n, po, cb);
    __shared__ int s[256];
    int base = lb * 1024;
    int sum = 0;
    for (int i = threadIdx.x; i < 1024; i += 256) {
        int idx = base + i;
        sum += (idx < n) ? cntAll[cb + idx] : 0;
    }
    s[threadIdx.x] = sum;
    __syncthreads();
    for (int off = 128; off; off >>= 1) {
        if (threadIdx.x < off) s[threadIdx.x] += s[threadIdx.x + off];
        __syncthreads();
    }
    if (threadIdx.x == 0) part[po + lb] = s[0];
}

__global__ void scan2f(int* part) {
    __shared__ int s[128];
    int t = threadIdx.x;
    int seg = (t < NB0) ? 0 : (t < NB0 + NB1) ? 1 : (t < NBT) ? 2 : 3;
    int v = (t < NBT) ? part[t] : 0;
    s[t] = v;
    __syncthreads();
    for (int off = 1; off < 128; off <<= 1) {
        int add = 0;
        if (t >= off) {
            int u = t - off;
            int segu = (u < NB0) ? 0 : (u < NB0 + NB1) ? 1 : (u < NBT) ? 2 : 3;
            if (segu == seg) add = s[u];
        }
        __syncthreads();
        s[t] += add;
        __syncthreads();
    }
    if (t < NBT) part[t] = s[t] - v;
}

__global__ void scan3f(const int* __restrict__ cntAll, const int* __restrict__ part,
                       int* __restrict__ rp0, int* __restrict__ rp1,
                       int* __restrict__ rp2) {
    int lb, n, po, cb;
    layer_of(blockIdx.x, lb, n, po, cb);
    int* row_ptr;
    if (cb == 0)        row_ptr = rp0;
    else if (cb == NN1) row_ptr = rp1;
    else                row_ptr = rp2;

    __shared__ int s[256];
    int base = lb * 1024;
    int v[4];
    int sum = 0;
    #pragma unroll
    for (int j = 0; j < 4; ++j) {
        int idx = base + threadIdx.x * 4 + j;
        v[j] = (idx < n) ? cntAll[cb + idx] : 0;
        sum += v[j];
    }
    s[threadIdx.x] = sum;
    __syncthreads();
    for (int off = 1; off < 256; off <<= 1) {
        int t = (threadIdx.x >= off) ? s[threadIdx.x - off] : 0;
        __syncthreads();
        s[threadIdx.x] += t;
        __syncthreads();
    }
    int off0 = part[po + lb] + s[threadIdx.x] - sum;
    #pragma unroll
    for (int j = 0; j < 4; ++j) {
        int idx = base + threadIdx.x * 4 + j;
        if (idx < n) {
            row_ptr[idx] = off0;
            off0 += v[j];
            if (idx == n - 1) row_ptr[n] = off0;
        }
    }
}

// ================= K3: atomic-free placement ================================
__global__ __launch_bounds__(256)
void place_all(const int* __restrict__ e0s, const int* __restrict__ e0d,
               const int* __restrict__ e1s, const int* __restrict__ e1d,
               const int* __restrict__ e2s, const int* __restrict__ e2d,
               const int* __restrict__ pos0, const int* __restrict__ pos1,
               const int* __restrict__ pos2, const int* __restrict__ cntp,
               const int* __restrict__ rp0, const int* __restrict__ rp1,
               const int* __restrict__ rp2,
               int* __restrict__ eidx0, int* __restrict__ eidx1,
               int* __restrict__ eidx2) {
    int b = blockIdx.x;
    int tid = threadIdx.x;
    if (b < HB0) {
        int e = b * 256 + tid;
        if (e < EE0) {
            int d = e0d[e];
            int g = e >> 15;
            int p = rp0[d] + cntp[(size_t)g * NTOT + d] + pos0[e];
            eidx0[p] = e0s[e];
        }
    } else if (b < HB0 + HB1) {
        int e = (b - HB0) * 256 + tid;
        if (e < EE1) {
            int d = e1d[e];
            int g = e >> 14;
            int p = rp1[d] + cntp[(size_t)g * NTOT + NN1 + d] + pos1[e];
            eidx1[p] = e1s[e];
        }
    } else {
        int e = (b - HB0 - HB1) * 256 + tid;
        if (e < EE2) {
            int d = e2d[e];
            int g = e >> 13;
            int p = rp2[d] + cntp[(size_t)g * NTOT + NN1 + NN2 + d] + pos2[e];
            eidx2[p] = e2s[e];
        }
    }
}

// ================= pull aggregation (fp32 accum, bf16 out, mean folded) ======

// D=100, gather from fp32 x; 4x neighbor unroll.
__global__ __launch_bounds__(256)
void agg100_f(const float* __restrict__ x, const int* __restrict__ rp,
              const int* __restrict__ eidx, ushort* __restrict__ out, int nNodes) {
    int node = blockIdx.x * 4 + (threadIdx.x >> 6);
    if (node >= nNodes) return;
    int l = threadIdx.x & 63;
    bool act = l < 50;
    int beg = rp[node], end = rp[node + 1];
    float a0 = 0.f, a1 = 0.f;
    int j = beg;
    for (; j + 3 < end; j += 4) {
        int s0 = eidx[j], s1 = eidx[j + 1], s2 = eidx[j + 2], s3 = eidx[j + 3];
        if (act) {
            float2 v0 = *reinterpret_cast<const float2*>(x + (size_t)s0 * DIN + l * 2);
            float2 v1 = *reinterpret_cast<const float2*>(x + (size_t)s1 * DIN + l * 2);
            float2 v2 = *reinterpret_cast<const float2*>(x + (size_t)s2 * DIN + l * 2);
            float2 v3 = *reinterpret_cast<const float2*>(x + (size_t)s3 * DIN + l * 2);
            a0 += v0.x + v1.x + v2.x + v3.x;
            a1 += v0.y + v1.y + v2.y + v3.y;
        }
    }
    for (; j < end; ++j) {
        int s0 = eidx[j];
        if (act) {
            float2 v0 = *reinterpret_cast<const float2*>(x + (size_t)s0 * DIN + l * 2);
            a0 += v0.x; a1 += v0.y;
        }
    }
    float inv = 1.0f / fmaxf((float)(end - beg), 1.0f);
    if (act) {
        uint o = (uint)f2bf(a0 * inv) | ((uint)f2bf(a1 * inv) << 16);
        *reinterpret_cast<uint*>(out + (size_t)node * DIN + l * 2) = o;
    }
}

__global__ __launch_bounds__(256)
void agg256_b(const ushort* __restrict__ h, const int* __restrict__ rp,
              const int* __restrict__ eidx, ushort* __restrict__ out, int nNodes) {
    int node = blockIdx.x * 4 + (threadIdx.x >> 6);
    if (node >= nNodes) return;
    int l = threadIdx.x & 63;
    int beg = rp[node], end = rp[node + 1];
    float a0 = 0.f, a1 = 0.f, a2 = 0.f, a3 = 0.f;
    int j = beg;
    for (; j + 3 < end; j += 4) {
        int s0 = eidx[j], s1 = eidx[j + 1], s2 = eidx[j + 2], s3 = eidx[j + 3];
        uint2 v0 = *reinterpret_cast<const uint2*>(h + (size_t)s0 * DH + l * 4);
        uint2 v1 = *reinterpret_cast<const uint2*>(h + (size_t)s1 * DH + l * 4);
        uint2 v2 = *reinterpret_cast<const uint2*>(h + (size_t)s2 * DH + l * 4);
        uint2 v3 = *reinterpret_cast<const uint2*>(h + (size_t)s3 * DH + l * 4);
        a0 += bf2f(v0.x & 0xffffu) + bf2f(v1.x & 0xffffu) + bf2f(v2.x & 0xffffu) + bf2f(v3.x & 0xffffu);
        a1 += bf2f(v0.x >> 16)     + bf2f(v1.x >> 16)     + bf2f(v2.x >> 16)     + bf2f(v3.x >> 16);
        a2 += bf2f(v0.y & 0xffffu) + bf2f(v1.y & 0xffffu) + bf2f(v2.y & 0xffffu) + bf2f(v3.y & 0xffffu);
        a3 += bf2f(v0.y >> 16)     + bf2f(v1.y >> 16)     + bf2f(v2.y >> 16)     + bf2f(v3.y >> 16);
    }
    for (; j < end; ++j) {
        int s0 = eidx[j];
        uint2 v0 = *reinterpret_cast<const uint2*>(h + (size_t)s0 * DH + l * 4);
        a0 += bf2f(v0.x & 0xffffu);
        a1 += bf2f(v0.x >> 16);
        a2 += bf2f(v0.y & 0xffffu);
        a3 += bf2f(v0.y >> 16);
    }
    float inv = 1.0f / fmaxf((float)(end - beg), 1.0f);
    uint2 o;
    o.x = (uint)f2bf(a0 * inv) | ((uint)f2bf(a1 * inv) << 16);
    o.y = (uint)f2bf(a2 * inv) | ((uint)f2bf(a3 * inv) << 16);
    *reinterpret_cast<uint2*>(out + (size_t)node * DH + l * 4) = o;
}

// ================= dual MFMA GEMM ===========================================
// A2F32: pass-2 operand is fp32 row-major; converted to bf16 during LDS stage.
template <int RELU, int OUTBF, int A2F32>
__global__ __launch_bounds__(256)
void gemm_dual(const ushort* __restrict__ A1, int K1, int S1, int str1,
               const void* __restrict__ A2, int K2, int S2, int str2,
               const ushort* __restrict__ B1p, const ushort* __restrict__ B2p,
               const float* __restrict__ bias, void* __restrict__ Cv,
               int M, int N, int NB, int NBW, int Cstride) {
    __shared__ ushort At[2][2048];

    const int tid = threadIdx.x;
    const int w = tid >> 6;
    const int l = tid & 63;
    const int m0 = blockIdx.x * 64;
    const int S = S1 + S2;

    f32x4 acc[4][4];
    #pragma unroll
    for (int m = 0; m < 4; ++m)
        #pragma unroll
        for (int i = 0; i < 4; ++i)
            acc[m][i] = f32x4{0.f, 0.f, 0.f, 0.f};

    auto stage = [&](int s, int buf) {
        int r  = tid >> 2;
        int kc = tid & 3;
        int row = m0 + r;
        U16B v;
        v.u4.x = v.u4.y = v.u4.z = v.u4.w = 0u;
        if (s < S1) {
            int k = s * 32 + (kc << 3);
            if (row < M && k < K1) {
                const ushort* p = A1 + (size_t)row * str1 + k;
                v.u2[0] = *reinterpret_cast<const uint2*>(p);
                v.u2[1] = *reinterpret_cast<const uint2*>(p + 4);
                if (k + 8 > K1) {
                    #pragma unroll
                    for (int j = 0; j < 8; ++j)
                        if (k + j >= K1) v.us[j] = 0;
                }
            }
        } else {
            int ks = s - S1;
            int k = ks * 32 + (kc << 3);
            if (row < M && k < K2) {
                if (A2F32) {
                    const float* p = (const float*)A2 + (size_t)row * str2 + k;
                    float4 f0 = *reinterpret_cast<const float4*>(p);
                    float4 f1 = *reinterpret_cast<const float4*>(p + 4);
                    v.us[0] = f2bf(f0.x); v.us[1] = f2bf(f0.y);
                    v.us[2] = f2bf(f0.z); v.us[3] = f2bf(f0.w);
                    v.us[4] = f2bf(f1.x); v.us[5] = f2bf(f1.y);
                    v.us[6] = f2bf(f1.z); v.us[7] = f2bf(f1.w);
                } else {
                    const ushort* p = (const ushort*)A2 + (size_t)row * str2 + k;
                    v.u2[0] = *reinterpret_cast<const uint2*>(p);
                    v.u2[1] = *reinterpret_cast<const uint2*>(p + 4);
                }
                if (k + 8 > K2) {
                    #pragma unroll
                    for (int j = 0; j < 8; ++j)
                        if (k + j >= K2) v.us[j] = 0;
                }
            }
        }
        int slot = ((r >> 4) << 6) | (r & 15) | (kc << 4);
        *reinterpret_cast<bhalf8*>(&At[buf][slot * 8]) = v.s8;
    };

    stage(0, 0);
    __syncthreads();

    for (int s = 0; s < S; ++s) {
        int buf = s & 1;
        if (s + 1 < S) stage(s + 1, buf ^ 1);

        const ushort* Bp; int ks;
        if (s < S1) { Bp = B1p; ks = s; }
        else        { Bp = B2p; ks = s - S1; }

        bhalf8 a[4];
        #pragma unroll
        for (int m = 0; m < 4; ++m)
            a[m] = *reinterpret_cast<bhalf8*>(&At[buf][((m << 6) | l) * 8]);

        #pragma unroll
        for (int i = 0; i < 4; ++i) {
            if (i < NBW) {
                int c = w * NBW + i;
                if (c < NB) {
                    bhalf8 b = *reinterpret_cast<const bhalf8*>(
                        Bp + ((size_t)(ks * NB + c) * 64 + l) * 8);
                    #pragma unroll
                    for (int m = 0; m < 4; ++m)
                        acc[m][i] = __builtin_amdgcn_mfma_f32_16x16x32_bf16(
                            a[m], b, acc[m][i], 0, 0, 0);
                }
            }
        }
        __syncthreads();
    }

    #pragma unroll
    for (int i = 0; i < 4; ++i) {
        if (i >= NBW) continue;
        int c = w * NBW + i;
        if (c >= NB) continue;
        int col = (c << 4) | (l & 15);
        if (col >= N) continue;
        float bb = bias[col];
        #pragma unroll
        for (int m = 0; m < 4; ++m) {
            #pragma unroll
            for (int e = 0; e < 4; ++e) {
                int row = m0 + (m << 4) + ((l >> 4) << 2) + e;
                if (row < M) {
                    float v = acc[m][i][e] + bb;
                    if (RELU) v = fmaxf(v, 0.0f);
                    if (OUTBF)
                        ((ushort*)Cv)[(size_t)row * Cstride + col] = f2bf(v);
                    else
                        ((float*)Cv)[(size_t)row * Cstride + col] = v;
                }
            }
        }
    }
}

// ================= log_softmax over 47 classes ==============================
__global__ void log_softmax_47(const float* __restrict__ z, float* __restrict__ out) {
    int row = blockIdx.x;
    int lane = threadIdx.x;
    float v = (lane < DOUT) ? z[(size_t)row * DOUT + lane] : -INFINITY;
    float m = v;
    #pragma unroll
    for (int off = 32; off; off >>= 1) m = fmaxf(m, __shfl_xor(m, off));
    float e = (lane < DOUT) ? expf(v - m) : 0.0f;
    float s = e;
    #pragma unroll
    for (int off = 32; off; off >>= 1) s += __shfl_xor(s, off);
    if (lane < DOUT) out[(size_t)row * DOUT + lane] = v - m - logf(s);
}

// ================= launch ====================================================
extern "C" void kernel_launch(void* const* d_in, const int* in_sizes, int n_in,
                              void* d_out, int out_size, void* d_ws, size_t ws_size,
                              hipStream_t stream) {
    const float* x   = (const float*)d_in[0];
    const int* e0s   = (const int*)d_in[1];
    const int* e0d   = (const int*)d_in[2];
    const int* e1s   = (const int*)d_in[3];
    const int* e1d   = (const int*)d_in[4];
    const int* e2s   = (const int*)d_in[5];
    const int* e2d   = (const int*)d_in[6];
    const float* Wl0 = (const float*)d_in[7];
    const float* Wr0 = (const float*)d_in[8];
    const float* b0  = (const float*)d_in[9];
    const float* Wl1 = (const float*)d_in[10];
    const float* Wr1 = (const float*)d_in[11];
    const float* b1  = (const float*)d_in[12];
    const float* Wl2 = (const float*)d_in[13];
    const float* Wr2 = (const float*)d_in[14];
    const float* b2  = (const float*)d_in[15];

    char* ws = (char*)d_ws;
    size_t off = 0;
    auto alloc = [&](size_t bytes) -> void* {
        void* p = ws + off;
        off += (bytes + 255) & ~(size_t)255;
        return p;
    };

    ushort* agg0b = (ushort*)alloc((size_t)NN1 * DIN * 2);
    ushort* h1    = (ushort*)alloc((size_t)NN1 * DH * 2);
    ushort* agg1b = (ushort*)alloc((size_t)NN2 * DH * 2);
    ushort* h2    = (ushort*)alloc((size_t)NN2 * DH * 2);
    ushort* agg2b = (ushort*)alloc((size_t)NN3 * DH * 2);
    float*  z     = (float*)alloc((size_t)NN3 * DOUT * 4);

    ushort* Bp0l = (ushort*)alloc((size_t)4 * 16 * 64 * 8 * 2);
    ushort* Bp0r = (ushort*)alloc((size_t)4 * 16 * 64 * 8 * 2);
    ushort* Bp1l = (ushort*)alloc((size_t)8 * 16 * 64 * 8 * 2);
    ushort* Bp1r = (ushort*)alloc((size_t)8 * 16 * 64 * 8 * 2);
    ushort* Bp2l = (ushort*)alloc((size_t)8 * 3 * 64 * 8 * 2);
    ushort* Bp2r = (ushort*)alloc((size_t)8 * 3 * 64 * 8 * 2);

    int* cntp   = (int*)alloc((size_t)NGMAX * NTOT * 4);   // 22.8 MB, no memset needed
    int* cntAll = (int*)alloc((size_t)NTOT * 4);
    int* pos0   = (int*)alloc((size_t)EE0 * 4);
    int* pos1   = (int*)alloc((size_t)EE1 * 4);
    int* pos2   = (int*)alloc((size_t)EE2 * 4);
    int* rp0    = (int*)alloc((size_t)(NN1 + 1) * 4);
    int* eidx0  = (int*)alloc((size_t)EE0 * 4);
    int* rp1    = (int*)alloc((size_t)(NN2 + 1) * 4);
    int* eidx1  = (int*)alloc((size_t)EE1 * 4);
    int* rp2    = (int*)alloc((size_t)(NN3 + 1) * 4);
    int* eidx2  = (int*)alloc((size_t)EE2 * 4);
    int* part   = (int*)alloc(256 * 4);

    // ---- K1: LDS histogram + rank (1024-thread blocks) ; weight pack ----
    hist_lds<<<HLT, 1024, 0, stream>>>(e0d, e1d, e2d, cntp, pos0, pos1, pos2);
    pack_all<<<108, 256, 0, stream>>>(Wl0, Wr0, Wl1, Wr1, Wl2, Wr2,
                                      Bp0l, Bp0r, Bp1l, Bp1r, Bp2l, Bp2r);

    // ---- K2: group scan + CSR scans ----
    combine_parts<<<(NTOT + 255) / 256, 256, 0, stream>>>(cntp, cntAll);
    scan1f<<<NBT, 256, 0, stream>>>(cntAll, part);
    scan2f<<<1, 128, 0, stream>>>(part);
    scan3f<<<NBT, 256, 0, stream>>>(cntAll, part, rp0, rp1, rp2);

    // ---- K3: atomic-free placement ----
    place_all<<<HBE, 256, 0, stream>>>(e0s, e0d, e1s, e1d, e2s, e2d,
                                       pos0, pos1, pos2, cntp,
                                       rp0, rp1, rp2, eidx0, eidx1, eidx2);

    // ---- layer 0 (dense x operand converted in-GEMM; no global conv) ----
    agg100_f<<<(NN1 + 3) / 4, 256, 0, stream>>>(x, rp0, eidx0, agg0b, NN1);
    gemm_dual<1, 1, 1><<<(NN1 + 63) / 64, 256, 0, stream>>>(
        agg0b, DIN, 4, DIN, (const void*)x, DIN, 4, DIN, Bp0l, Bp0r, b0, h1,
        NN1, DH, 16, 4, DH);

    // ---- layer 1 ----
    agg256_b<<<(NN2 + 3) / 4, 256, 0, stream>>>(h1, rp1, eidx1, agg1b, NN2);
    gemm_dual<1, 1, 0><<<(NN2 + 63) / 64, 256, 0, stream>>>(
        agg1b, DH, 8, DH, (const void*)h1, DH, 8, DH, Bp1l, Bp1r, b1, h2,
        NN2, DH, 16, 4, DH);

    // ---- layer 2 ----
    agg256_b<<<(NN3 + 3) / 4, 256, 0, stream>>>(h2, rp2, eidx2, agg2b, NN3);
    gemm_dual<0, 0, 0><<<(NN3 + 63) / 64, 256, 0, stream>>>(
        agg2b, DH, 8, DH, (const void*)h2, DH, 8, DH, Bp2l, Bp2r, b2, z,
        NN3, DOUT, 3, 1, DOUT);

    // ---- log_softmax ----
    log_softmax_47<<<NN3, 64, 0, stream>>>(z, (float*)d_out);
}